// Round 8
// baseline (3341.002 us; speedup 1.0000x reference)
//
#include <hip/hip_runtime.h>
#include <math.h>

// ---------------------------------------------------------------------------
// JKNet: 2-layer GCN (sym-norm A+I) + sum-JK + linear + log_softmax.
// Round 8: aggregation via block-local LDS fp32 atomics (fire-and-forget
// ds_add_f32 -> no load->FMA register dependency; loads stream freely).
// Edges sorted to 64-node dst blocks; dstLocal packed in src word. Per-node
// CSR replaced by 1563-entry block CSR. bf16 MFMA GEMMs unchanged.
// ---------------------------------------------------------------------------

#define NPAD (1 << 17)
#define CHUNK 1024
#define NB_MAX 4096      // block-CSR array sizes (need ceil(n/64)+1)

typedef __attribute__((ext_vector_type(8))) short short8;
typedef __attribute__((ext_vector_type(4))) float f32x4;

__device__ inline unsigned short f2bf(float f) {
    unsigned u = __builtin_bit_cast(unsigned, f);
    return (unsigned short)((u + 0x7fffu + ((u >> 16) & 1u)) >> 16);
}
__device__ inline float bflo(unsigned u) { return __builtin_bit_cast(float, u << 16); }
__device__ inline float bfhi(unsigned u) { return __builtin_bit_cast(float, u & 0xffff0000u); }

// ---- degree histogram (for dis) -------------------------------------------
__global__ void hist_node(const int* __restrict__ dst, int* __restrict__ cnt, int E) {
    int e = blockIdx.x * 256 + threadIdx.x;
    if (e < E) atomicAdd(&cnt[dst[e]], 1);
}

__global__ void dis_k(const int* __restrict__ cnt, float* __restrict__ dis, int n) {
    int i = blockIdx.x * 256 + threadIdx.x;
    if (i < n) dis[i] = rsqrtf((float)(cnt[i] + 1));   // +1 self-loop
}

// ---- block (64-node) histogram from node counts ---------------------------
__global__ void bsum_k(const int* __restrict__ cnt, int* __restrict__ bcnt, int n) {
    int idx = blockIdx.x * 64 + threadIdx.x;
    int v = (idx < n) ? cnt[idx] : 0;
#pragma unroll
    for (int off = 32; off > 0; off >>= 1) v += __shfl_down(v, off, 64);
    if (threadIdx.x == 0) bcnt[blockIdx.x] = v;
}

// ---- generic exclusive scan (3 kernels), n elements -----------------------
__global__ void scan_partial(const int* __restrict__ cnt, int* __restrict__ partial, int n) {
    __shared__ int sdata[4];
    int b = blockIdx.x, t = threadIdx.x;
    int base = b * CHUNK;
    int sum = 0;
    for (int i = t; i < CHUNK; i += 256) {
        int idx = base + i;
        if (idx < n) sum += cnt[idx];
    }
#pragma unroll
    for (int off = 32; off > 0; off >>= 1) sum += __shfl_down(sum, off, 64);
    if ((t & 63) == 0) sdata[t >> 6] = sum;
    __syncthreads();
    if (t == 0) partial[b] = sdata[0] + sdata[1] + sdata[2] + sdata[3];
}

__global__ void scan_small(int* partial, int nblk) {
    if (threadIdx.x == 0 && blockIdx.x == 0) {
        int acc = 0;
        for (int i = 0; i < nblk; i++) { int v = partial[i]; partial[i] = acc; acc += v; }
    }
}

__global__ void scan_final(const int* __restrict__ cnt, const int* __restrict__ partial,
                           int* __restrict__ offs, int* __restrict__ cursor, int n) {
    __shared__ int wsum[4];
    int b = blockIdx.x, t = threadIdx.x;
    int lane = t & 63, w = t >> 6;
    int base = b * CHUNK + t * 4;
    int v[4];
#pragma unroll
    for (int j = 0; j < 4; j++) v[j] = (base + j < n) ? cnt[base + j] : 0;
    int s4 = v[0] + v[1] + v[2] + v[3];
    int inc = s4;
#pragma unroll
    for (int off = 1; off < 64; off <<= 1) {
        int x = __shfl_up(inc, off, 64);
        if (lane >= off) inc += x;
    }
    if (lane == 63) wsum[w] = inc;
    __syncthreads();
    int woff = 0;
    for (int i = 0; i < 4; i++) if (i < w) woff += wsum[i];
    int pos = partial[b] + woff + (inc - s4);
#pragma unroll
    for (int j = 0; j < 4; j++) {
        int idx = base + j;
        if (idx < n) {
            offs[idx] = pos;
            cursor[idx] = pos;
            pos += v[j];
        }
    }
}

__global__ void sentinel_k(int* __restrict__ boffs, int nb, int E) {
    if (threadIdx.x == 0 && blockIdx.x == 0) boffs[nb] = E;
}

// ---- permute: bucket by dst range; cursor per 64-node dst block -----------
// eadj word0 = (dstLocal<<26) | src ; word1 = fp32 bits of dis[s]*dis[d]
__global__ void permute_bucket(const int* __restrict__ src, const int* __restrict__ dst,
                               const float* __restrict__ dis,
                               int* __restrict__ bcursor, int2* __restrict__ eadj,
                               int E, int lo, int hi) {
    int e = blockIdx.x * 256 + threadIdx.x;
    if (e < E) {
        int d = dst[e];
        if (d >= lo && d < hi) {
            int s = src[e];
            int pos = atomicAdd(&bcursor[d >> 6], 1);
            float wt = dis[s] * dis[d];
            eadj[pos] = make_int2(((d & 63) << 26) | s, __float_as_int(wt));
        }
    }
}

// ---- W cast+transpose: Wt[n][k] = bf16(W[k][n]) ---------------------------
__global__ void wcast(const float* __restrict__ W, unsigned short* __restrict__ Wt, int K) {
    int i = blockIdx.x * 256 + threadIdx.x;
    if (i < K * 128) {
        int k = i >> 7, nn = i & 127;
        Wt[nn * K + k] = f2bf(W[i]);
    }
}

// ---- MFMA GEMM: Hb[n,128](bf16) = A[n,K] @ W[K,128] -----------------------
template<bool ABF16>
__global__ __launch_bounds__(256) void gemm_mfma(const void* __restrict__ Ap,
                                                 const unsigned short* __restrict__ Wt,
                                                 unsigned short* __restrict__ Hb,
                                                 int n, int K) {
    __shared__ unsigned short bs[128 * 136];
    const int tid = threadIdx.x;
    const int wave = tid >> 6, lane = tid & 63;
    const int quad = lane >> 4, mrow = lane & 15;
    const int arow_g = blockIdx.x * 64 + wave * 16 + mrow;
    const int arow = arow_g < n ? arow_g : n - 1;

    f32x4 acc[8];
#pragma unroll
    for (int t = 0; t < 8; t++) acc[t] = (f32x4){0.f, 0.f, 0.f, 0.f};

    const float* Af = (const float*)Ap;
    const unsigned short* Ab = (const unsigned short*)Ap;

    for (int kc = 0; kc < K; kc += 128) {
        __syncthreads();
        for (int i = tid; i < 2048; i += 256) {
            int row = i >> 4, c8 = i & 15;
            *(short8*)&bs[row * 136 + c8 * 8] = *(const short8*)&Wt[row * K + kc + c8 * 8];
        }
        __syncthreads();
#pragma unroll
        for (int kt = 0; kt < 128; kt += 32) {
            union { short8 v; unsigned short u[8]; } A;
            if (ABF16) {
                A.v = *(const short8*)&Ab[(size_t)arow * K + kc + kt + quad * 8];
            } else {
                const float* ap = &Af[(size_t)arow * K + kc + kt + quad * 8];
                float4 p0 = *(const float4*)ap;
                float4 p1 = *(const float4*)(ap + 4);
                A.u[0] = f2bf(p0.x); A.u[1] = f2bf(p0.y);
                A.u[2] = f2bf(p0.z); A.u[3] = f2bf(p0.w);
                A.u[4] = f2bf(p1.x); A.u[5] = f2bf(p1.y);
                A.u[6] = f2bf(p1.z); A.u[7] = f2bf(p1.w);
            }
#pragma unroll
            for (int nt = 0; nt < 8; nt++) {
                short8 B = *(const short8*)&bs[(nt * 16 + mrow) * 136 + kt + quad * 8];
                acc[nt] = __builtin_amdgcn_mfma_f32_16x16x32_bf16(A.v, B, acc[nt], 0, 0, 0);
            }
        }
    }
    const int drow0 = blockIdx.x * 64 + wave * 16 + quad * 4;
#pragma unroll
    for (int r = 0; r < 4; r++) {
        int dr = drow0 + r;
        if (dr < n) {
#pragma unroll
            for (int nt = 0; nt < 8; nt++)
                Hb[(size_t)dr * 128 + nt * 16 + mrow] = f2bf(acc[nt][r]);
        }
    }
}

// ---- aggregation: block = 64 dst nodes, LDS fp32 accumulator, edge stream -
// Edge loop has NO accumulate dependency: uniform (scalar) metadata loads,
// coalesced 256 B row loads, fire-and-forget ds_add_f32.
template<bool FUSE>
__global__ __launch_bounds__(256) void agg_k(const unsigned short* __restrict__ Hb,
                                             const int2* __restrict__ eadj,
                                             const int* __restrict__ boffs,
                                             const float* __restrict__ dis,
                                             const float* __restrict__ bias,
                                             unsigned short* __restrict__ outb,
                                             const unsigned short* __restrict__ x1b,
                                             const float* __restrict__ lw,
                                             const float* __restrict__ lb,
                                             float* __restrict__ out, int n) {
    __shared__ float acc[64 * 128];          // 32 KB
    const int w = threadIdx.x >> 6, lane = threadIdx.x & 63;
    const int nb0 = blockIdx.x << 6;
    for (int i = threadIdx.x; i < 64 * 128; i += 256) acc[i] = 0.f;
    __syncthreads();

    const int estart = boffs[blockIdx.x];
    const int eend   = boffs[blockIdx.x + 1];
    const int total  = eend - estart;
    const int chunk  = (total + 3) >> 2;
    int js = estart + w * chunk;
    int je = js + chunk < eend ? js + chunk : eend;
    js = __builtin_amdgcn_readfirstlane(js);   // force scalar loop bounds ->
    je = __builtin_amdgcn_readfirstlane(je);   // eadj loads become s_load
    const unsigned* Hu = (const unsigned*)Hb;

    int j = js;
    for (; j + 8 <= je; j += 8) {
        int2 e[8];
#pragma unroll
        for (int k = 0; k < 8; k++) e[k] = eadj[j + k];
        unsigned u[8];
#pragma unroll
        for (int k = 0; k < 8; k++)
            u[k] = Hu[(size_t)((unsigned)e[k].x & 0x03FFFFFFu) * 64 + lane];
#pragma unroll
        for (int k = 0; k < 8; k++) {
            float wt = __int_as_float(e[k].y);
            int dl = (int)((unsigned)e[k].x >> 26);
            float* ap = &acc[dl * 128 + 2 * lane];
            atomicAdd(ap,     bflo(u[k]) * wt);
            atomicAdd(ap + 1, bfhi(u[k]) * wt);
        }
    }
    for (; j < je; j++) {
        int2 e = eadj[j];
        unsigned u = Hu[(size_t)((unsigned)e.x & 0x03FFFFFFu) * 64 + lane];
        float wt = __int_as_float(e.y);
        int dl = (int)((unsigned)e.x >> 26);
        float* ap = &acc[dl * 128 + 2 * lane];
        atomicAdd(ap,     bflo(u) * wt);
        atomicAdd(ap + 1, bfhi(u) * wt);
    }
    __syncthreads();

    // finalize: wave w owns local nodes w*16 .. w*16+15
#pragma unroll 1
    for (int i = 0; i < 16; i++) {
        int dl = w * 16 + i;
        int node = nb0 + dl;
        bool valid = node < n;
        int nd = valid ? node : n - 1;
        float a0 = acc[dl * 128 + 2 * lane];
        float a1 = acc[dl * 128 + 2 * lane + 1];
        float dd = dis[nd], sn = dd * dd;
        unsigned us = Hu[(size_t)nd * 64 + lane];
        float2 bb = ((const float2*)bias)[lane];
        a0 = fmaf(bflo(us), sn, a0) + bb.x;
        a1 = fmaf(bfhi(us), sn, a1) + bb.y;
        a0 = a0 > 0.f ? a0 : 0.f;
        a1 = a1 > 0.f ? a1 : 0.f;
        if (!FUSE) {
            if (valid) {
                unsigned pk = ((unsigned)f2bf(a1) << 16) | (unsigned)f2bf(a0);
                ((unsigned*)outb)[(size_t)node * 64 + lane] = pk;
            }
        } else {
            unsigned xu = ((const unsigned*)x1b)[(size_t)nd * 64 + lane];
            acc[dl * 128 + 2 * lane]     = a0 + bflo(xu);   // jk vector for head
            acc[dl * 128 + 2 * lane + 1] = a1 + bfhi(xu);
        }
    }
    if (FUSE) {
        // wave-local slots: within-wave ds ordering suffices, no barrier
#pragma unroll 1
        for (int i = 0; i < 16; i++) {
            int dl = w * 16 + i;
            int node = nb0 + dl;
            bool act = (node < n) && (lane < 41);
            float val = 0.f;
            if (act) {
#pragma unroll 4
                for (int f = 0; f < 128; f++) val = fmaf(acc[dl * 128 + f], lw[f * 41 + lane], val);
                val += lb[lane];
            }
            float m = act ? val : -INFINITY;
#pragma unroll
            for (int off = 32; off > 0; off >>= 1) m = fmaxf(m, __shfl_xor(m, off, 64));
            float e = act ? expf(val - m) : 0.f;
#pragma unroll
            for (int off = 32; off > 0; off >>= 1) e += __shfl_xor(e, off, 64);
            if (act) out[(size_t)node * 41 + lane] = val - m - logf(e);
        }
    }
}

extern "C" void kernel_launch(void* const* d_in, const int* in_sizes, int n_in,
                              void* d_out, int out_size, void* d_ws, size_t ws_size,
                              hipStream_t stream) {
    const float* x  = (const float*)d_in[0];
    const int*   ei = (const int*)d_in[1];
    const float* W1 = (const float*)d_in[2];
    const float* b1 = (const float*)d_in[3];
    const float* W2 = (const float*)d_in[4];
    const float* b2 = (const float*)d_in[5];
    const float* lw = (const float*)d_in[6];
    const float* lb = (const float*)d_in[7];
    float* out = (float*)d_out;

    const int n = in_sizes[0] / 256;   // 100000
    const int E = in_sizes[1] / 2;     // 1600000
    const int* src = ei;
    const int* dst = ei + E;
    const int nb = (n + 63) / 64;      // 1563 dst blocks

    // workspace layout
    int*   cnt     = (int*)d_ws;                       // NPAD
    int*   bcnt    = cnt + NPAD;                       // NB_MAX
    int*   boffs   = bcnt + NB_MAX;                    // NB_MAX (+1 sentinel)
    int*   bcursor = boffs + NB_MAX;                   // NB_MAX
    int*   partial = bcursor + NB_MAX;                 // 1024
    float* dis     = (float*)(partial + 1024);         // NPAD
    size_t Epad    = ((size_t)E + 255) & ~(size_t)255;
    int2*  eadj    = (int2*)(dis + NPAD);              // Epad pairs
    unsigned short* Wt1 = (unsigned short*)(eadj + Epad);  // 256*128
    unsigned short* Wt2 = Wt1 + 256 * 128;                 // 128*128
    unsigned short* Hb  = Wt2 + 128 * 128;                 // n*128
    unsigned short* X1b = Hb + (size_t)n * 128;            // n*128

    hipMemsetAsync(cnt, 0, (size_t)n * sizeof(int), stream);
    hipMemsetAsync(bcnt, 0, (size_t)nb * sizeof(int), stream);
    wcast<<<(256 * 128 + 255) / 256, 256, 0, stream>>>(W1, Wt1, 256);
    wcast<<<(128 * 128 + 255) / 256, 256, 0, stream>>>(W2, Wt2, 128);

    // degree -> dis; block histogram -> scan -> sorted (src,w,dstLocal)
    hist_node<<<(E + 255) / 256, 256, 0, stream>>>(dst, cnt, E);
    dis_k<<<(n + 255) / 256, 256, 0, stream>>>(cnt, dis, n);
    bsum_k<<<nb, 64, 0, stream>>>(cnt, bcnt, n);
    {
        const int nscan = (nb + CHUNK - 1) / CHUNK;
        scan_partial<<<nscan, 256, 0, stream>>>(bcnt, partial, nb);
        scan_small<<<1, 64, 0, stream>>>(partial, nscan);
        scan_final<<<nscan, 256, 0, stream>>>(bcnt, partial, boffs, bcursor, nb);
        sentinel_k<<<1, 64, 0, stream>>>(boffs, nb, E);
    }
    {
        const int NBUCKET = 2;
        int W = ((n + NBUCKET * 64 - 1) / (NBUCKET * 64)) * 64;  // 64-aligned
        for (int p = 0; p < NBUCKET; p++) {
            int lo = p * W, hi = lo + W < n ? lo + W : n;
            permute_bucket<<<(E + 255) / 256, 256, 0, stream>>>(src, dst, dis, bcursor, eadj, E, lo, hi);
        }
    }

    // layer 1
    gemm_mfma<false><<<(n + 63) / 64, 256, 0, stream>>>(x, Wt1, Hb, n, 256);
    agg_k<false><<<nb, 256, 0, stream>>>(Hb, eadj, boffs, dis, b1, X1b,
                                         nullptr, nullptr, nullptr, nullptr, n);

    // layer 2 + fused JK head
    gemm_mfma<true><<<(n + 63) / 64, 256, 0, stream>>>(X1b, Wt2, Hb, n, 128);
    agg_k<true><<<nb, 256, 0, stream>>>(Hb, eadj, boffs, dis, b2, nullptr,
                                        X1b, lw, lb, out, n);
}